// Round 19
// baseline (137.650 us; speedup 1.0000x reference)
//
#include <hip/hip_runtime.h>
#include <math.h>

#define B_DIM 2048
#define D_DIM 512
#define F_DIM 16384
#define K_TOP 3

typedef __attribute__((ext_vector_type(8))) short bf16x8;
typedef __attribute__((ext_vector_type(4))) float f32x4;

#define GL16(gsrc, ldst) \
  __builtin_amdgcn_global_load_lds( \
      (__attribute__((address_space(1))) const void*)(gsrc), \
      (__attribute__((address_space(3))) void*)(ldst), 16, 0, 0)

#define WAITVMCNT(n) asm volatile("s_waitcnt vmcnt(" #n ")" ::: "memory")
#define BARRIER() do { asm volatile("" ::: "memory"); \
    __builtin_amdgcn_s_barrier(); \
    asm volatile("" ::: "memory"); } while (0)

// lexicographic "better": larger value wins; tie -> lower index (lax.top_k)
__device__ __forceinline__ bool better(float v, int c, float w, int j) {
    return (v > w) || (v == w && c < j);
}

__device__ __forceinline__ void ins3(float v, int c,
    float& v0, int& i0, float& v1, int& i1, float& v2, int& i2)
{
    if (!better(v, c, v2, i2)) return;
    if (better(v, c, v1, i1)) {
        v2 = v1; i2 = i1;
        if (better(v, c, v0, i0)) { v1 = v0; i1 = i0; v0 = v; i0 = c; }
        else { v1 = v; i1 = c; }
    } else { v2 = v; i2 = c; }
}

// monotonic u32 key: (ordered bf16 desc) then (col asc)
__device__ __forceinline__ uint okey(uint b16, int col) {
    uint m = 0x8000u + ((b16 >> 15) * 0x7FFFu);
    return ((b16 ^ m) << 14) | (uint)(16383 - col);
}

// branchless descending top-8 insert (umax/umin ladder)
__device__ __forceinline__ void insK8(uint k, uint* V) {
#pragma unroll
    for (int j = 0; j < 8; ++j) {
        uint hi = V[j] > k ? V[j] : k;
        uint lo = V[j] > k ? k : V[j];
        V[j] = hi; k = lo;
    }
}

// branchless descending top-3 insert on three scalars
__device__ __forceinline__ void insK3(uint k, uint& V0, uint& V1, uint& V2) {
    uint h0 = V0 > k ? V0 : k, l0 = V0 > k ? k : V0; V0 = h0; k = l0;
    uint h1 = V1 > k ? V1 : k, l1 = V1 > k ? k : V1; V1 = h1; k = l1;
    V2 = V2 > k ? V2 : k;
}

__device__ __forceinline__ float bf2f(ushort u) {
    return __uint_as_float((uint)u << 16);
}

__device__ __forceinline__ uint pk(uint lo, uint hi) {
    return (hi & 0xFFFF0000u) | (lo >> 16);
}

__device__ __forceinline__ ushort bf_t(float v) {
    return (ushort)(__float_as_uint(v) >> 16);
}

// ---------------------------------------------------------------------------
// Kernel 0: converts. blocks 0..1023 = We f32->bf16; 1024..1151 = x.
// 512 threads, 2 uint4 (16 elems) per lane.
// ---------------------------------------------------------------------------
__global__ __launch_bounds__(512) void convert_kernel(
    const float* __restrict__ We, ushort* __restrict__ We_bf,
    const float* __restrict__ x, ushort* __restrict__ x_bf)
{
    const float* src; ushort* dst; int i;
    if (blockIdx.x < 1024) { src = We; dst = We_bf; i = blockIdx.x * 1024 + threadIdx.x * 2; }
    else                   { src = x;  dst = x_bf;  i = (blockIdx.x - 1024) * 1024 + threadIdx.x * 2; }
#pragma unroll
    for (int u = 0; u < 2; ++u) {
        float4 a = ((const float4*)src)[(i + u) * 2];
        float4 b = ((const float4*)src)[(i + u) * 2 + 1];
        uint4 o;
        o.x = pk(__float_as_uint(a.x), __float_as_uint(a.y));
        o.y = pk(__float_as_uint(a.z), __float_as_uint(a.w));
        o.z = pk(__float_as_uint(b.x), __float_as_uint(b.y));
        o.w = pk(__float_as_uint(b.z), __float_as_uint(b.w));
        ((uint4*)dst)[i + u] = o;
    }
}

// ---------------------------------------------------------------------------
// Kernel 1 (GEMM+TRGRAM tail-fusion): blocks 0..2047 = verified gemm;
// blocks 2048..2559 = REGISTER-LEAN trgram (16-d chunks, 3 float4 staging
// regs, uint2 stores, 12.5KB LDS) so the co-compiled high-water VGPR mark
// returns to the gemm branch's level.
// ---------------------------------------------------------------------------
__global__ __launch_bounds__(256) void gemmtr_kernel(
    const ushort* __restrict__ xb, const ushort* __restrict__ web,
    const float* __restrict__ be, uint* __restrict__ packed,
    const float* __restrict__ Wd, const float* __restrict__ Wd1,
    const float* __restrict__ Wd2, ushort* __restrict__ WdT,
    ushort* __restrict__ Wd1T, ushort* __restrict__ Wd2T,
    float* __restrict__ gramp, int* __restrict__ flags3F)
{
    __shared__ __align__(16) char smem[32768];
    const int t = threadIdx.x;

    if (blockIdx.x >= 2048) {
        // ---------------- trgram branch (register-lean) ----------------
        const int id2 = blockIdx.x - 2048;           // 0..511
        if (t < 24)
            ((uint4*)flags3F)[id2 * 24 + t] = make_uint4(0, 0, 0, 0);
        float* tA = (float*)smem;                    // [16][65]
        float* tB = tA + 16 * 65;
        float* tC = tB + 16 * 65;                    // ends at 12480 B
        const int f0 = (id2 >> 1) << 6;
        const int dbase = (id2 & 1) << 8;            // half of D
        const int lrow = t >> 4, lcq = t & 15;       // load: row 0..15, colq 0..15
        const int flw = t >> 2, dg = t & 3;          // write: f-col 0..63, d-group 0..3
        float pp = 0, p1 = 0, p2 = 0, s11 = 0, s22 = 0;
        float4 a0, b0, c0;
#define LOADCH(ch) do { \
    const size_t base_ = (size_t)(dbase + (ch) * 16 + lrow) * F_DIM + f0 + lcq * 4; \
    a0 = *(const float4*)(Wd  + base_); \
    b0 = *(const float4*)(Wd1 + base_); \
    c0 = *(const float4*)(Wd2 + base_); \
} while (0)
        LOADCH(0);
#pragma unroll 1
        for (int ch = 0; ch < 16; ++ch) {
            if (ch) __syncthreads();     // prior write-out done reading LDS
            const int lb = lrow * 65 + lcq * 4;
            tA[lb + 0] = a0.x; tA[lb + 1] = a0.y; tA[lb + 2] = a0.z; tA[lb + 3] = a0.w;
            tB[lb + 0] = b0.x; tB[lb + 1] = b0.y; tB[lb + 2] = b0.z; tB[lb + 3] = b0.w;
            tC[lb + 0] = c0.x; tC[lb + 1] = c0.y; tC[lb + 2] = c0.z; tC[lb + 3] = c0.w;
            if (ch < 15) LOADCH(ch + 1); // next chunk flies under write-out
            __syncthreads();
            ushort ua[4], ub[4], uc[4];
#pragma unroll
            for (int j = 0; j < 4; ++j) {
                float va = tA[(dg * 4 + j) * 65 + flw];
                float vb = tB[(dg * 4 + j) * 65 + flw];
                float vc = tC[(dg * 4 + j) * 65 + flw];
                pp  = fmaf(va, va, pp);
                p1  = fmaf(va, vb, p1);
                p2  = fmaf(va, vc, p2);
                s11 = fmaf(vb, vb, s11);
                s22 = fmaf(vc, vc, s22);
                ua[j] = bf_t(va); ub[j] = bf_t(vb); uc[j] = bf_t(vc);
            }
            const size_t doff = (size_t)(f0 + flw) * D_DIM + dbase + ch * 16 + dg * 4;
            *(uint2*)&WdT[doff]  = make_uint2(ua[0] | ((uint)ua[1] << 16),
                                              ua[2] | ((uint)ua[3] << 16));
            *(uint2*)&Wd1T[doff] = make_uint2(ub[0] | ((uint)ub[1] << 16),
                                              ub[2] | ((uint)ub[3] << 16));
            *(uint2*)&Wd2T[doff] = make_uint2(uc[0] | ((uint)uc[1] << 16),
                                              uc[2] | ((uint)uc[3] << 16));
        }
#undef LOADCH
        // reduce the 4 dg-partials (consecutive lanes share flw)
#pragma unroll
        for (int mk = 1; mk <= 2; mk <<= 1) {
            pp  += __shfl_xor(pp, mk);
            p1  += __shfl_xor(p1, mk);
            p2  += __shfl_xor(p2, mk);
            s11 += __shfl_xor(s11, mk);
            s22 += __shfl_xor(s22, mk);
        }
        if ((t & 3) == 0) {
            float* gp = gramp + (size_t)(id2 & 1) * 5 * F_DIM;
            const int fcol = f0 + (t >> 2);
            gp[fcol] = pp;
            gp[F_DIM + fcol] = p1;
            gp[2 * F_DIM + fcol] = p2;
            gp[3 * F_DIM + fcol] = s11;
            gp[4 * F_DIM + fcol] = s22;
        }
        return;
    }

    // ---------------- gemm branch (verified R13/R17 kernel) ----------------
    ushort* As = (ushort*)smem;        // [2][4096]
    ushort* Bs = As + 8192;
    const int id = blockIdx.x;
    const int r = id & 127;
    const int bx = ((r & 7) << 4) + (r >> 3);   // column tile; bx/16 == id%8
    const int by = id >> 7;                     // row tile
    const int l = t & 63;
    const int w = t >> 6;
    const int wr = w >> 1, wc = w & 1;
    const int bm0 = by << 7;
    const int fn0 = bx << 7;
    const int frow = l & 15;
    const int q = l >> 4;

    const int srow = t >> 2;
    const int sgr = (t & 3) ^ ((t >> 3) & 3);
    const int soff = sgr << 3;
    const ushort* gA0 = xb + (size_t)(bm0 + srow) * D_DIM + soff;
    const ushort* gA1 = xb + (size_t)(bm0 + 64 + srow) * D_DIM + soff;
    const ushort* gB0 = web + (size_t)(fn0 + srow) * D_DIM + soff;
    const ushort* gB1 = web + (size_t)(fn0 + 64 + srow) * D_DIM + soff;

#define STAGE(bufp, koff) do { \
    GL16(gA0 + (koff), (char*)As + (bufp) * 8192 + t * 16); \
    GL16(gA1 + (koff), (char*)As + (bufp) * 8192 + 4096 + t * 16); \
    GL16(gB0 + (koff), (char*)Bs + (bufp) * 8192 + t * 16); \
    GL16(gB1 + (koff), (char*)Bs + (bufp) * 8192 + 4096 + t * 16); \
} while (0)

    f32x4 acc[4][4];
#pragma unroll
    for (int m = 0; m < 4; ++m)
#pragma unroll
        for (int n = 0; n < 4; ++n) acc[m][n] = (f32x4)(0.f);

    const int qs = (q ^ ((frow >> 1) & 3)) << 3;
    const int aoff = (wr * 64 + frow) * 32 + qs;
    const int boff = (wc * 64 + frow) * 32 + qs;

    STAGE(0, 0);

#pragma unroll 1
    for (int t16 = 0; t16 < 16; ++t16) {
        const int cur = t16 & 1;
        if (t16 < 15) {
            STAGE(cur ^ 1, (t16 + 1) * 32);
            WAITVMCNT(4);    // my buf[cur] loads landed; next tile's 4 flying
        } else {
            WAITVMCNT(0);
        }
        BARRIER();           // all waves' buf[cur] data visible
        const ushort* Ab = As + cur * 4096 + aoff;
        const ushort* Bb = Bs + cur * 4096 + boff;
        bf16x8 af[4], bfr[4];
#pragma unroll
        for (int m = 0; m < 4; ++m) af[m] = *(const bf16x8*)(Ab + m * 512);
#pragma unroll
        for (int n = 0; n < 4; ++n) bfr[n] = *(const bf16x8*)(Bb + n * 512);
#pragma unroll
        for (int m = 0; m < 4; ++m)
#pragma unroll
            for (int n = 0; n < 4; ++n)
                acc[m][n] = __builtin_amdgcn_mfma_f32_16x16x32_bf16(
                    af[m], bfr[n], acc[m][n], 0, 0, 0);
        BARRIER();           // readers done before buf[cur] overwrite
    }
#undef STAGE

    float bias[4];
#pragma unroll
    for (int n = 0; n < 4; ++n) bias[n] = be[fn0 + wc * 64 + n * 16 + frow];

    const int colb = fn0 + wc * 64 + frow;
    const int rowbase = bm0 + wr * 64 + (q << 2);
    const int tile2 = (bx << 1) + wc;
#pragma unroll
    for (int m = 0; m < 4; ++m) {
#pragma unroll
        for (int i = 0; i < 4; ++i) {
            uint V0 = 0, V1 = 0, V2 = 0;
#pragma unroll
            for (int n = 0; n < 4; ++n) {
                float v = acc[m][n][i] + bias[n];
                uint key = okey(__float_as_uint(v) >> 16, colb + n * 16);
                insK3(key, V0, V1, V2);
            }
#pragma unroll
            for (int mk = 1; mk <= 8; mk <<= 1) {
                uint o0 = (uint)__shfl_xor((int)V0, mk);
                uint o1 = (uint)__shfl_xor((int)V1, mk);
                uint o2 = (uint)__shfl_xor((int)V2, mk);
                insK3(o0, V0, V1, V2);
                insK3(o1, V0, V1, V2);
                insK3(o2, V0, V1, V2);
            }
            if (frow == 0) {
                uint* dp = packed + (size_t)(rowbase + m * 16 + i) * 768 + tile2 * 3;
                dp[0] = V0; dp[1] = V1; dp[2] = V2;
            }
        }
    }
}

// ---------------------------------------------------------------------------
// Kernel 2: FUSED merge + refine + child + aux + recon, one block per row.
// gram is two partials (gramp[0], gramp[5F]) summed at use.
// ---------------------------------------------------------------------------
__global__ __launch_bounds__(512) void mrcra_kernel(
    const uint* __restrict__ packed,
    const float* __restrict__ x, const float* __restrict__ We,
    const float* __restrict__ be,
    const float* __restrict__ We1, const float* __restrict__ be1,
    const float* __restrict__ We2, const float* __restrict__ be2,
    const float* __restrict__ gramp,
    const ushort* __restrict__ WdT, const float* __restrict__ bd,
    const ushort* __restrict__ Wd1T, const float* __restrict__ bd1,
    const ushort* __restrict__ Wd2T, const float* __restrict__ bd2,
    int* __restrict__ flagP, int* __restrict__ flag1, int* __restrict__ flag2,
    float* __restrict__ auxpart, float* __restrict__ cntpart,
    float* __restrict__ out)
{
    __shared__ int sc8[8];
    __shared__ float sv[8];
    __shared__ int si[8];
    __shared__ float sval[3], sdot[3][2], scv[3], sterm[3], sact[3];
    __shared__ int sidx[3], swin[3];
    const int row = blockIdx.x;
    const int t = threadIdx.x;
    const int wv = t >> 6, l = t & 63;

    // phase 1: merge 768 keys -> top-8 (wave 0)
    if (t < 64) {
        const uint* p = packed + (size_t)row * 768;
        uint V[8] = {0, 0, 0, 0, 0, 0, 0, 0};
#pragma unroll
        for (int m = 0; m < 12; ++m) {
            uint k = p[t + (m << 6)];
            if (k > V[7]) insK8(k, V);
        }
#pragma unroll
        for (int mk = 1; mk < 64; mk <<= 1) {
            uint o[8];
#pragma unroll
            for (int j = 0; j < 8; ++j) o[j] = (uint)__shfl_xor((int)V[j], mk);
#pragma unroll
            for (int j = 0; j < 8; ++j)
                if (o[j] > V[7]) insK8(o[j], V);
        }
        if (t == 0) {
#pragma unroll
            for (int j = 0; j < 8; ++j)
                sc8[j] = 16383 - (int)(V[j] & 16383u);
        }
    }
    __syncthreads();

    // phase 2: exact f32 refine of 8 candidates (8 waves)
    {
        const int f = sc8[wv];
        const float* xr = x + (size_t)row * D_DIM;
        const float* wp = We + (size_t)f * D_DIM;
        float s = 0.f;
#pragma unroll
        for (int m = 0; m < 8; ++m) { int e = l + (m << 6); s = fmaf(xr[e], wp[e], s); }
#pragma unroll
        for (int mk = 1; mk < 64; mk <<= 1) s += __shfl_xor(s, mk);
        if (l == 0) { sv[wv] = s + be[f]; si[wv] = f; }
    }
    __syncthreads();
    if (t == 0) {
        float v0 = -INFINITY, v1 = -INFINITY, v2 = -INFINITY;
        int i0 = 0x7fffffff, i1 = 0x7fffffff, i2 = 0x7fffffff;
        for (int k = 0; k < 8; ++k) ins3(sv[k], si[k], v0, i0, v1, i1, v2, i2);
        sval[0] = v0; sidx[0] = i0;
        sval[1] = v1; sidx[1] = i1;
        sval[2] = v2; sidx[2] = i2;
    }
    __syncthreads();

    // phase 3: child dots (6 waves)
    if (wv < 6) {
        const int p = wv >> 1, mt = wv & 1;
        const int f = sidx[p];
        const float* wp = (mt ? We2 : We1) + (size_t)f * D_DIM;
        const float* xr = x + (size_t)row * D_DIM;
        float s = 0.f;
#pragma unroll
        for (int m = 0; m < 8; ++m) { int e = l + (m << 6); s = fmaf(xr[e], wp[e], s); }
#pragma unroll
        for (int mk = 1; mk < 64; mk <<= 1) s += __shfl_xor(s, mk);
        if (l == 0) sdot[p][mt] = s + (mt ? be2 : be1)[f];
    }
    __syncthreads();

    // phase 4: winner / flags / aux terms (3 threads)
    if (t < 3) {
        const int p = t;
        const float a = sval[p];
        const int f = sidx[p];
        float m1 = (a != 0.f) ? sdot[p][0] : 0.f;
        float m2 = (a != 0.f) ? sdot[p][1] : 0.f;
        bool win = m1 > m2;
        float fa1 = win ? m1 : 0.f;
        float fa2 = win ? 0.f : m2;
        float cv = win ? fa1 : fa2;
        scv[p] = cv; swin[p] = win ? 1 : 0;
        flagP[f] = 1;
        if (fa1 != 0.f) flag1[f] = 1;
        if (fa2 != 0.f) flag2[f] = 1;
        const int gsel = win ? 1 : 2;
        const int ssel = win ? 3 : 4;
        const float pp = gramp[f] + gramp[5 * F_DIM + f];
        const float pc = gramp[gsel * F_DIM + f] + gramp[(5 + gsel) * F_DIM + f];
        const float cc = gramp[ssel * F_DIM + f] + gramp[(5 + ssel) * F_DIM + f];
        const float dot = a * (a * pp + cv * pc);
        const float nx = fabsf(a) * sqrtf(pp);
        const float ny2 = a * a * pp + 2.f * a * cv * pc + cv * cv * cc;
        const float ny = sqrtf(fmaxf(ny2, 0.f));
        const float cosv = dot / (fmaxf(nx, 1e-8f) * fmaxf(ny, 1e-8f));
        sterm[p] = (a > 0.f) ? fmaxf(0.f, 0.7f - cosv) : 0.f;
        sact[p] = (a > 0.f) ? 1.f : 0.f;
    }
    __syncthreads();
    if (t == 0) {
        auxpart[row] = sterm[0] + sterm[1] + sterm[2];
        cntpart[row] = sact[0] + sact[1] + sact[2];
    }

    // phase 5: recon (all 512 threads, thread t = dim d)
    const int d = t;
    float o = bd[d] + bd1[d] + bd2[d];
#pragma unroll
    for (int k = 0; k < 3; ++k) {
        const int f = sidx[k];
        const float a = sval[k];
        const float c = scv[k];
        const int win = swin[k];
        const size_t off = (size_t)f * D_DIM + d;
        o = fmaf(a, bf2f(WdT[off]), o);
        if (c != 0.f) {
            const ushort* wt = win ? Wd1T : Wd2T;
            o = fmaf(c, bf2f(wt[off]), o);
        }
    }
    out[(size_t)row * D_DIM + d] = o;
}

// ---------------------------------------------------------------------------
// Kernel 3: count flags, finish aux (2048 partials), write scalars (f32)
// ---------------------------------------------------------------------------
__global__ __launch_bounds__(256) void finalize_kernel(
    const int* __restrict__ flagP, const int* __restrict__ flag1,
    const int* __restrict__ flag2,
    const float* __restrict__ auxpart, const float* __restrict__ cntpart,
    float* __restrict__ out)
{
    const int t = threadIdx.x;
    int sp = 0, s1 = 0, s2 = 0;
    for (int f = t; f < F_DIM; f += 256) { sp += flagP[f]; s1 += flag1[f]; s2 += flag2[f]; }
    float asum = 0.f, acnt = 0.f;
    for (int i = t; i < B_DIM; i += 256) { asum += auxpart[i]; acnt += cntpart[i]; }
#pragma unroll
    for (int m = 1; m < 64; m <<= 1) {
        sp += __shfl_xor(sp, m); s1 += __shfl_xor(s1, m); s2 += __shfl_xor(s2, m);
        asum += __shfl_xor(asum, m); acnt += __shfl_xor(acnt, m);
    }
    __shared__ int red[3][4];
    __shared__ float fred[2][4];
    const int w = t >> 6;
    if ((t & 63) == 0) {
        red[0][w] = sp; red[1][w] = s1; red[2][w] = s2;
        fred[0][w] = asum; fred[1][w] = acnt;
    }
    __syncthreads();
    if (t == 0) {
        float np_ = (float)(red[0][0] + red[0][1] + red[0][2] + red[0][3]);
        float n1_ = (float)(red[1][0] + red[1][1] + red[1][2] + red[1][3]);
        float n2_ = (float)(red[2][0] + red[2][1] + red[2][2] + red[2][3]);
        float as = fred[0][0] + fred[0][1] + fred[0][2] + fred[0][3];
        float ac = fred[1][0] + fred[1][1] + fred[1][2] + fred[1][3];
        const size_t base = (size_t)B_DIM * D_DIM;
        out[base + 0] = np_;
        out[base + 1] = n1_;
        out[base + 2] = n2_;
        out[base + 3] = as / (ac + 1e-8f);
    }
}

extern "C" void kernel_launch(void* const* d_in, const int* in_sizes, int n_in,
                              void* d_out, int out_size, void* d_ws, size_t ws_size,
                              hipStream_t stream)
{
    (void)in_sizes; (void)n_in; (void)out_size; (void)ws_size;
    const float* x   = (const float*)d_in[0];
    const float* We  = (const float*)d_in[1];
    const float* be  = (const float*)d_in[2];
    const float* Wd  = (const float*)d_in[3];
    const float* bd  = (const float*)d_in[4];
    const float* We1 = (const float*)d_in[5];
    const float* be1 = (const float*)d_in[6];
    const float* Wd1 = (const float*)d_in[7];
    const float* bd1 = (const float*)d_in[8];
    const float* We2 = (const float*)d_in[9];
    const float* be2 = (const float*)d_in[10];
    const float* Wd2 = (const float*)d_in[11];
    const float* bd2 = (const float*)d_in[12];
    float* out = (float*)d_out;

    // workspace layout (~74 MB)
    ushort* x_bf  = (ushort*)d_ws;                             // B*D
    ushort* We_bf = x_bf + (size_t)B_DIM * D_DIM;              // F*D
    ushort* WdT   = We_bf + (size_t)F_DIM * D_DIM;             // F*D
    ushort* Wd1T  = WdT + (size_t)F_DIM * D_DIM;               // F*D
    ushort* Wd2T  = Wd1T + (size_t)F_DIM * D_DIM;              // F*D
    uint*   packed = (uint*)(Wd2T + (size_t)F_DIM * D_DIM);    // B*768
    float*  gramp = (float*)(packed + (size_t)B_DIM * 768);    // 10F (2 halves)
    int*    flagP = (int*)(gramp + 10 * F_DIM);                // F (contig w/ flag1,flag2)
    int*    flag1 = flagP + F_DIM;                             // F
    int*    flag2 = flag1 + F_DIM;                             // F
    float*  auxpart = (float*)(flag2 + F_DIM);                 // B
    float*  cntpart = auxpart + B_DIM;                         // B

    convert_kernel<<<1152, 512, 0, stream>>>(We, We_bf, x, x_bf);

    gemmtr_kernel<<<2560, 256, 0, stream>>>(
        x_bf, We_bf, be, packed,
        Wd, Wd1, Wd2, WdT, Wd1T, Wd2T, gramp, flagP);

    mrcra_kernel<<<B_DIM, 512, 0, stream>>>(
        packed, x, We, be, We1, be1, We2, be2, gramp,
        WdT, bd, Wd1T, bd1, Wd2T, bd2,
        flagP, flag1, flag2, auxpart, cntpart, out);

    finalize_kernel<<<1, 256, 0, stream>>>(
        flagP, flag1, flag2, auxpart, cntpart, out);
}

// Round 20
// 129.431 us; speedup vs baseline: 1.0635x; 1.0635x over previous
//
#include <hip/hip_runtime.h>
#include <math.h>

#define B_DIM 2048
#define D_DIM 512
#define F_DIM 16384
#define K_TOP 3

typedef __attribute__((ext_vector_type(8))) short bf16x8;
typedef __attribute__((ext_vector_type(4))) float f32x4;

#define GL16(gsrc, ldst) \
  __builtin_amdgcn_global_load_lds( \
      (__attribute__((address_space(1))) const void*)(gsrc), \
      (__attribute__((address_space(3))) void*)(ldst), 16, 0, 0)

#define WAITVMCNT(n) asm volatile("s_waitcnt vmcnt(" #n ")" ::: "memory")
#define BARRIER() do { asm volatile("" ::: "memory"); \
    __builtin_amdgcn_s_barrier(); \
    asm volatile("" ::: "memory"); } while (0)

// lexicographic "better": larger value wins; tie -> lower index (lax.top_k)
__device__ __forceinline__ bool better(float v, int c, float w, int j) {
    return (v > w) || (v == w && c < j);
}

__device__ __forceinline__ void ins3(float v, int c,
    float& v0, int& i0, float& v1, int& i1, float& v2, int& i2)
{
    if (!better(v, c, v2, i2)) return;
    if (better(v, c, v1, i1)) {
        v2 = v1; i2 = i1;
        if (better(v, c, v0, i0)) { v1 = v0; i1 = i0; v0 = v; i0 = c; }
        else { v1 = v; i1 = c; }
    } else { v2 = v; i2 = c; }
}

// monotonic u32 key: (ordered bf16 desc) then (col asc)
__device__ __forceinline__ uint okey(uint b16, int col) {
    uint m = 0x8000u + ((b16 >> 15) * 0x7FFFu);
    return ((b16 ^ m) << 14) | (uint)(16383 - col);
}

// branchless descending top-8 insert (umax/umin ladder)
__device__ __forceinline__ void insK8(uint k, uint* V) {
#pragma unroll
    for (int j = 0; j < 8; ++j) {
        uint hi = V[j] > k ? V[j] : k;
        uint lo = V[j] > k ? k : V[j];
        V[j] = hi; k = lo;
    }
}

// branchless descending top-3 insert on three scalars
__device__ __forceinline__ void insK3(uint k, uint& V0, uint& V1, uint& V2) {
    uint h0 = V0 > k ? V0 : k, l0 = V0 > k ? k : V0; V0 = h0; k = l0;
    uint h1 = V1 > k ? V1 : k, l1 = V1 > k ? k : V1; V1 = h1; k = l1;
    V2 = V2 > k ? V2 : k;
}

__device__ __forceinline__ float bf2f(ushort u) {
    return __uint_as_float((uint)u << 16);
}

__device__ __forceinline__ uint pk(uint lo, uint hi) {
    return (hi & 0xFFFF0000u) | (lo >> 16);
}

__device__ __forceinline__ ushort bf_t(float v) {
    return (ushort)(__float_as_uint(v) >> 16);
}

// ---------------------------------------------------------------------------
// Kernel 0: converts. blocks 0..1023 = We f32->bf16; 1024..1151 = x.
// 512 threads, 2 uint4 (16 elems) per lane.
// ---------------------------------------------------------------------------
__global__ __launch_bounds__(512) void convert_kernel(
    const float* __restrict__ We, ushort* __restrict__ We_bf,
    const float* __restrict__ x, ushort* __restrict__ x_bf)
{
    const float* src; ushort* dst; int i;
    if (blockIdx.x < 1024) { src = We; dst = We_bf; i = blockIdx.x * 1024 + threadIdx.x * 2; }
    else                   { src = x;  dst = x_bf;  i = (blockIdx.x - 1024) * 1024 + threadIdx.x * 2; }
#pragma unroll
    for (int u = 0; u < 2; ++u) {
        float4 a = ((const float4*)src)[(i + u) * 2];
        float4 b = ((const float4*)src)[(i + u) * 2 + 1];
        uint4 o;
        o.x = pk(__float_as_uint(a.x), __float_as_uint(a.y));
        o.y = pk(__float_as_uint(a.z), __float_as_uint(a.w));
        o.z = pk(__float_as_uint(b.x), __float_as_uint(b.y));
        o.w = pk(__float_as_uint(b.z), __float_as_uint(b.w));
        ((uint4*)dst)[i + u] = o;
    }
}

// ---------------------------------------------------------------------------
// Kernel 1 (GEMM+TRGRAM tail-fusion): blocks 0..2047 = verified gemm
// (double-buffer GL16, counted vmcnt(4), XCD swizzle, fused key top-3);
// blocks 2048..2559 = trgram (64-f stripe x half-D, 8 chunks of 32 d,
// 24.4KB LDS within the 32KB arena), dispatched LAST so they backfill CUs
// as gemm blocks retire — no data dependency. (Verified R18 kernel.)
// ---------------------------------------------------------------------------
__global__ __launch_bounds__(256) void gemmtr_kernel(
    const ushort* __restrict__ xb, const ushort* __restrict__ web,
    const float* __restrict__ be, uint* __restrict__ packed,
    const float* __restrict__ Wd, const float* __restrict__ Wd1,
    const float* __restrict__ Wd2, ushort* __restrict__ WdT,
    ushort* __restrict__ Wd1T, ushort* __restrict__ Wd2T,
    float* __restrict__ gramp, int* __restrict__ flags3F)
{
    __shared__ __align__(16) char smem[32768];
    const int t = threadIdx.x;

    if (blockIdx.x >= 2048) {
        // ---------------- trgram branch ----------------
        const int id2 = blockIdx.x - 2048;           // 0..511
        if (t < 24)
            ((uint4*)flags3F)[id2 * 24 + t] = make_uint4(0, 0, 0, 0);
        float* tA = (float*)smem;                    // [32][65]
        float* tB = tA + 32 * 65;
        float* tC = tB + 32 * 65;                    // ends at 24960 B
        const int f0 = (id2 >> 1) << 6;
        const int dbase = (id2 & 1) << 8;            // half of D
        const int dl = t >> 3, fq = t & 7;           // load mapping
        const int flw = t >> 2, dg = t & 3;          // write mapping
        float pp = 0, p1 = 0, p2 = 0, s11 = 0, s22 = 0;
        float4 a0, a1, b0, b1, c0, c1;
#define LOADCH(ch) do { \
    const size_t base_ = (size_t)(dbase + (ch) * 32 + dl) * F_DIM + f0 + fq * 8; \
    a0 = *(const float4*)(Wd  + base_); a1 = *(const float4*)(Wd  + base_ + 4); \
    b0 = *(const float4*)(Wd1 + base_); b1 = *(const float4*)(Wd1 + base_ + 4); \
    c0 = *(const float4*)(Wd2 + base_); c1 = *(const float4*)(Wd2 + base_ + 4); \
} while (0)
        LOADCH(0);
#pragma unroll 1
        for (int ch = 0; ch < 8; ++ch) {
            if (ch) __syncthreads();     // prior write-out done reading LDS
            const int lb = dl * 65 + fq * 8;
            tA[lb + 0] = a0.x; tA[lb + 1] = a0.y; tA[lb + 2] = a0.z; tA[lb + 3] = a0.w;
            tA[lb + 4] = a1.x; tA[lb + 5] = a1.y; tA[lb + 6] = a1.z; tA[lb + 7] = a1.w;
            tB[lb + 0] = b0.x; tB[lb + 1] = b0.y; tB[lb + 2] = b0.z; tB[lb + 3] = b0.w;
            tB[lb + 4] = b1.x; tB[lb + 5] = b1.y; tB[lb + 6] = b1.z; tB[lb + 7] = b1.w;
            tC[lb + 0] = c0.x; tC[lb + 1] = c0.y; tC[lb + 2] = c0.z; tC[lb + 3] = c0.w;
            tC[lb + 4] = c1.x; tC[lb + 5] = c1.y; tC[lb + 6] = c1.z; tC[lb + 7] = c1.w;
            if (ch < 7) LOADCH(ch + 1);  // next chunk flies under write-out
            __syncthreads();
            ushort ua[8], ub[8], uc[8];
#pragma unroll
            for (int j = 0; j < 8; ++j) {
                float va = tA[(dg * 8 + j) * 65 + flw];
                float vb = tB[(dg * 8 + j) * 65 + flw];
                float vc = tC[(dg * 8 + j) * 65 + flw];
                pp  = fmaf(va, va, pp);
                p1  = fmaf(va, vb, p1);
                p2  = fmaf(va, vc, p2);
                s11 = fmaf(vb, vb, s11);
                s22 = fmaf(vc, vc, s22);
                ua[j] = bf_t(va); ub[j] = bf_t(vb); uc[j] = bf_t(vc);
            }
            const size_t doff = (size_t)(f0 + flw) * D_DIM + dbase + ch * 32 + dg * 8;
            *(uint4*)&WdT[doff] = make_uint4(
                ua[0] | ((uint)ua[1] << 16), ua[2] | ((uint)ua[3] << 16),
                ua[4] | ((uint)ua[5] << 16), ua[6] | ((uint)ua[7] << 16));
            *(uint4*)&Wd1T[doff] = make_uint4(
                ub[0] | ((uint)ub[1] << 16), ub[2] | ((uint)ub[3] << 16),
                ub[4] | ((uint)ub[5] << 16), ub[6] | ((uint)ub[7] << 16));
            *(uint4*)&Wd2T[doff] = make_uint4(
                uc[0] | ((uint)uc[1] << 16), uc[2] | ((uint)uc[3] << 16),
                uc[4] | ((uint)uc[5] << 16), uc[6] | ((uint)uc[7] << 16));
        }
#undef LOADCH
        // reduce the 4 dg-partials (consecutive lanes share flw)
#pragma unroll
        for (int mk = 1; mk <= 2; mk <<= 1) {
            pp  += __shfl_xor(pp, mk);
            p1  += __shfl_xor(p1, mk);
            p2  += __shfl_xor(p2, mk);
            s11 += __shfl_xor(s11, mk);
            s22 += __shfl_xor(s22, mk);
        }
        if ((t & 3) == 0) {
            float* gp = gramp + (size_t)(id2 & 1) * 5 * F_DIM;
            const int fcol = f0 + (t >> 2);
            gp[fcol] = pp;
            gp[F_DIM + fcol] = p1;
            gp[2 * F_DIM + fcol] = p2;
            gp[3 * F_DIM + fcol] = s11;
            gp[4 * F_DIM + fcol] = s22;
        }
        return;
    }

    // ---------------- gemm branch (verified R13/R17 kernel) ----------------
    ushort* As = (ushort*)smem;        // [2][4096]
    ushort* Bs = As + 8192;
    const int id = blockIdx.x;
    const int r = id & 127;
    const int bx = ((r & 7) << 4) + (r >> 3);   // column tile; bx/16 == id%8
    const int by = id >> 7;                     // row tile
    const int l = t & 63;
    const int w = t >> 6;
    const int wr = w >> 1, wc = w & 1;
    const int bm0 = by << 7;
    const int fn0 = bx << 7;
    const int frow = l & 15;
    const int q = l >> 4;

    const int srow = t >> 2;
    const int sgr = (t & 3) ^ ((t >> 3) & 3);
    const int soff = sgr << 3;
    const ushort* gA0 = xb + (size_t)(bm0 + srow) * D_DIM + soff;
    const ushort* gA1 = xb + (size_t)(bm0 + 64 + srow) * D_DIM + soff;
    const ushort* gB0 = web + (size_t)(fn0 + srow) * D_DIM + soff;
    const ushort* gB1 = web + (size_t)(fn0 + 64 + srow) * D_DIM + soff;

#define STAGE(bufp, koff) do { \
    GL16(gA0 + (koff), (char*)As + (bufp) * 8192 + t * 16); \
    GL16(gA1 + (koff), (char*)As + (bufp) * 8192 + 4096 + t * 16); \
    GL16(gB0 + (koff), (char*)Bs + (bufp) * 8192 + t * 16); \
    GL16(gB1 + (koff), (char*)Bs + (bufp) * 8192 + 4096 + t * 16); \
} while (0)

    f32x4 acc[4][4];
#pragma unroll
    for (int m = 0; m < 4; ++m)
#pragma unroll
        for (int n = 0; n < 4; ++n) acc[m][n] = (f32x4)(0.f);

    const int qs = (q ^ ((frow >> 1) & 3)) << 3;
    const int aoff = (wr * 64 + frow) * 32 + qs;
    const int boff = (wc * 64 + frow) * 32 + qs;

    STAGE(0, 0);

#pragma unroll 1
    for (int t16 = 0; t16 < 16; ++t16) {
        const int cur = t16 & 1;
        if (t16 < 15) {
            STAGE(cur ^ 1, (t16 + 1) * 32);
            WAITVMCNT(4);    // my buf[cur] loads landed; next tile's 4 flying
        } else {
            WAITVMCNT(0);
        }
        BARRIER();           // all waves' buf[cur] data visible
        const ushort* Ab = As + cur * 4096 + aoff;
        const ushort* Bb = Bs + cur * 4096 + boff;
        bf16x8 af[4], bfr[4];
#pragma unroll
        for (int m = 0; m < 4; ++m) af[m] = *(const bf16x8*)(Ab + m * 512);
#pragma unroll
        for (int n = 0; n < 4; ++n) bfr[n] = *(const bf16x8*)(Bb + n * 512);
#pragma unroll
        for (int m = 0; m < 4; ++m)
#pragma unroll
            for (int n = 0; n < 4; ++n)
                acc[m][n] = __builtin_amdgcn_mfma_f32_16x16x32_bf16(
                    af[m], bfr[n], acc[m][n], 0, 0, 0);
        BARRIER();           // readers done before buf[cur] overwrite
    }
#undef STAGE

    float bias[4];
#pragma unroll
    for (int n = 0; n < 4; ++n) bias[n] = be[fn0 + wc * 64 + n * 16 + frow];

    const int colb = fn0 + wc * 64 + frow;
    const int rowbase = bm0 + wr * 64 + (q << 2);
    const int tile2 = (bx << 1) + wc;
#pragma unroll
    for (int m = 0; m < 4; ++m) {
#pragma unroll
        for (int i = 0; i < 4; ++i) {
            uint V0 = 0, V1 = 0, V2 = 0;
#pragma unroll
            for (int n = 0; n < 4; ++n) {
                float v = acc[m][n][i] + bias[n];
                uint key = okey(__float_as_uint(v) >> 16, colb + n * 16);
                insK3(key, V0, V1, V2);
            }
#pragma unroll
            for (int mk = 1; mk <= 8; mk <<= 1) {
                uint o0 = (uint)__shfl_xor((int)V0, mk);
                uint o1 = (uint)__shfl_xor((int)V1, mk);
                uint o2 = (uint)__shfl_xor((int)V2, mk);
                insK3(o0, V0, V1, V2);
                insK3(o1, V0, V1, V2);
                insK3(o2, V0, V1, V2);
            }
            if (frow == 0) {
                uint* dp = packed + (size_t)(rowbase + m * 16 + i) * 768 + tile2 * 3;
                dp[0] = V0; dp[1] = V1; dp[2] = V2;
            }
        }
    }
}

// ---------------------------------------------------------------------------
// Kernel 2: FUSED merge + refine + child + aux + recon, one block per row.
// gram is two partials (gramp[0], gramp[5F]) summed at use.
// ---------------------------------------------------------------------------
__global__ __launch_bounds__(512) void mrcra_kernel(
    const uint* __restrict__ packed,
    const float* __restrict__ x, const float* __restrict__ We,
    const float* __restrict__ be,
    const float* __restrict__ We1, const float* __restrict__ be1,
    const float* __restrict__ We2, const float* __restrict__ be2,
    const float* __restrict__ gramp,
    const ushort* __restrict__ WdT, const float* __restrict__ bd,
    const ushort* __restrict__ Wd1T, const float* __restrict__ bd1,
    const ushort* __restrict__ Wd2T, const float* __restrict__ bd2,
    int* __restrict__ flagP, int* __restrict__ flag1, int* __restrict__ flag2,
    float* __restrict__ auxpart, float* __restrict__ cntpart,
    float* __restrict__ out)
{
    __shared__ int sc8[8];
    __shared__ float sv[8];
    __shared__ int si[8];
    __shared__ float sval[3], sdot[3][2], scv[3], sterm[3], sact[3];
    __shared__ int sidx[3], swin[3];
    const int row = blockIdx.x;
    const int t = threadIdx.x;
    const int wv = t >> 6, l = t & 63;

    // phase 1: merge 768 keys -> top-8 (wave 0)
    if (t < 64) {
        const uint* p = packed + (size_t)row * 768;
        uint V[8] = {0, 0, 0, 0, 0, 0, 0, 0};
#pragma unroll
        for (int m = 0; m < 12; ++m) {
            uint k = p[t + (m << 6)];
            if (k > V[7]) insK8(k, V);
        }
#pragma unroll
        for (int mk = 1; mk < 64; mk <<= 1) {
            uint o[8];
#pragma unroll
            for (int j = 0; j < 8; ++j) o[j] = (uint)__shfl_xor((int)V[j], mk);
#pragma unroll
            for (int j = 0; j < 8; ++j)
                if (o[j] > V[7]) insK8(o[j], V);
        }
        if (t == 0) {
#pragma unroll
            for (int j = 0; j < 8; ++j)
                sc8[j] = 16383 - (int)(V[j] & 16383u);
        }
    }
    __syncthreads();

    // phase 2: exact f32 refine of 8 candidates (8 waves)
    {
        const int f = sc8[wv];
        const float* xr = x + (size_t)row * D_DIM;
        const float* wp = We + (size_t)f * D_DIM;
        float s = 0.f;
#pragma unroll
        for (int m = 0; m < 8; ++m) { int e = l + (m << 6); s = fmaf(xr[e], wp[e], s); }
#pragma unroll
        for (int mk = 1; mk < 64; mk <<= 1) s += __shfl_xor(s, mk);
        if (l == 0) { sv[wv] = s + be[f]; si[wv] = f; }
    }
    __syncthreads();
    if (t == 0) {
        float v0 = -INFINITY, v1 = -INFINITY, v2 = -INFINITY;
        int i0 = 0x7fffffff, i1 = 0x7fffffff, i2 = 0x7fffffff;
        for (int k = 0; k < 8; ++k) ins3(sv[k], si[k], v0, i0, v1, i1, v2, i2);
        sval[0] = v0; sidx[0] = i0;
        sval[1] = v1; sidx[1] = i1;
        sval[2] = v2; sidx[2] = i2;
    }
    __syncthreads();

    // phase 3: child dots (6 waves)
    if (wv < 6) {
        const int p = wv >> 1, mt = wv & 1;
        const int f = sidx[p];
        const float* wp = (mt ? We2 : We1) + (size_t)f * D_DIM;
        const float* xr = x + (size_t)row * D_DIM;
        float s = 0.f;
#pragma unroll
        for (int m = 0; m < 8; ++m) { int e = l + (m << 6); s = fmaf(xr[e], wp[e], s); }
#pragma unroll
        for (int mk = 1; mk < 64; mk <<= 1) s += __shfl_xor(s, mk);
        if (l == 0) sdot[p][mt] = s + (mt ? be2 : be1)[f];
    }
    __syncthreads();

    // phase 4: winner / flags / aux terms (3 threads)
    if (t < 3) {
        const int p = t;
        const float a = sval[p];
        const int f = sidx[p];
        float m1 = (a != 0.f) ? sdot[p][0] : 0.f;
        float m2 = (a != 0.f) ? sdot[p][1] : 0.f;
        bool win = m1 > m2;
        float fa1 = win ? m1 : 0.f;
        float fa2 = win ? 0.f : m2;
        float cv = win ? fa1 : fa2;
        scv[p] = cv; swin[p] = win ? 1 : 0;
        flagP[f] = 1;
        if (fa1 != 0.f) flag1[f] = 1;
        if (fa2 != 0.f) flag2[f] = 1;
        const int gsel = win ? 1 : 2;
        const int ssel = win ? 3 : 4;
        const float pp = gramp[f] + gramp[5 * F_DIM + f];
        const float pc = gramp[gsel * F_DIM + f] + gramp[(5 + gsel) * F_DIM + f];
        const float cc = gramp[ssel * F_DIM + f] + gramp[(5 + ssel) * F_DIM + f];
        const float dot = a * (a * pp + cv * pc);
        const float nx = fabsf(a) * sqrtf(pp);
        const float ny2 = a * a * pp + 2.f * a * cv * pc + cv * cv * cc;
        const float ny = sqrtf(fmaxf(ny2, 0.f));
        const float cosv = dot / (fmaxf(nx, 1e-8f) * fmaxf(ny, 1e-8f));
        sterm[p] = (a > 0.f) ? fmaxf(0.f, 0.7f - cosv) : 0.f;
        sact[p] = (a > 0.f) ? 1.f : 0.f;
    }
    __syncthreads();
    if (t == 0) {
        auxpart[row] = sterm[0] + sterm[1] + sterm[2];
        cntpart[row] = sact[0] + sact[1] + sact[2];
    }

    // phase 5: recon (all 512 threads, thread t = dim d)
    const int d = t;
    float o = bd[d] + bd1[d] + bd2[d];
#pragma unroll
    for (int k = 0; k < 3; ++k) {
        const int f = sidx[k];
        const float a = sval[k];
        const float c = scv[k];
        const int win = swin[k];
        const size_t off = (size_t)f * D_DIM + d;
        o = fmaf(a, bf2f(WdT[off]), o);
        if (c != 0.f) {
            const ushort* wt = win ? Wd1T : Wd2T;
            o = fmaf(c, bf2f(wt[off]), o);
        }
    }
    out[(size_t)row * D_DIM + d] = o;
}

// ---------------------------------------------------------------------------
// Kernel 3: count flags, finish aux (2048 partials), write scalars (f32)
// ---------------------------------------------------------------------------
__global__ __launch_bounds__(256) void finalize_kernel(
    const int* __restrict__ flagP, const int* __restrict__ flag1,
    const int* __restrict__ flag2,
    const float* __restrict__ auxpart, const float* __restrict__ cntpart,
    float* __restrict__ out)
{
    const int t = threadIdx.x;
    int sp = 0, s1 = 0, s2 = 0;
    for (int f = t; f < F_DIM; f += 256) { sp += flagP[f]; s1 += flag1[f]; s2 += flag2[f]; }
    float asum = 0.f, acnt = 0.f;
    for (int i = t; i < B_DIM; i += 256) { asum += auxpart[i]; acnt += cntpart[i]; }
#pragma unroll
    for (int m = 1; m < 64; m <<= 1) {
        sp += __shfl_xor(sp, m); s1 += __shfl_xor(s1, m); s2 += __shfl_xor(s2, m);
        asum += __shfl_xor(asum, m); acnt += __shfl_xor(acnt, m);
    }
    __shared__ int red[3][4];
    __shared__ float fred[2][4];
    const int w = t >> 6;
    if ((t & 63) == 0) {
        red[0][w] = sp; red[1][w] = s1; red[2][w] = s2;
        fred[0][w] = asum; fred[1][w] = acnt;
    }
    __syncthreads();
    if (t == 0) {
        float np_ = (float)(red[0][0] + red[0][1] + red[0][2] + red[0][3]);
        float n1_ = (float)(red[1][0] + red[1][1] + red[1][2] + red[1][3]);
        float n2_ = (float)(red[2][0] + red[2][1] + red[2][2] + red[2][3]);
        float as = fred[0][0] + fred[0][1] + fred[0][2] + fred[0][3];
        float ac = fred[1][0] + fred[1][1] + fred[1][2] + fred[1][3];
        const size_t base = (size_t)B_DIM * D_DIM;
        out[base + 0] = np_;
        out[base + 1] = n1_;
        out[base + 2] = n2_;
        out[base + 3] = as / (ac + 1e-8f);
    }
}

extern "C" void kernel_launch(void* const* d_in, const int* in_sizes, int n_in,
                              void* d_out, int out_size, void* d_ws, size_t ws_size,
                              hipStream_t stream)
{
    (void)in_sizes; (void)n_in; (void)out_size; (void)ws_size;
    const float* x   = (const float*)d_in[0];
    const float* We  = (const float*)d_in[1];
    const float* be  = (const float*)d_in[2];
    const float* Wd  = (const float*)d_in[3];
    const float* bd  = (const float*)d_in[4];
    const float* We1 = (const float*)d_in[5];
    const float* be1 = (const float*)d_in[6];
    const float* Wd1 = (const float*)d_in[7];
    const float* bd1 = (const float*)d_in[8];
    const float* We2 = (const float*)d_in[9];
    const float* be2 = (const float*)d_in[10];
    const float* Wd2 = (const float*)d_in[11];
    const float* bd2 = (const float*)d_in[12];
    float* out = (float*)d_out;

    // workspace layout (~74 MB)
    ushort* x_bf  = (ushort*)d_ws;                             // B*D
    ushort* We_bf = x_bf + (size_t)B_DIM * D_DIM;              // F*D
    ushort* WdT   = We_bf + (size_t)F_DIM * D_DIM;             // F*D
    ushort* Wd1T  = WdT + (size_t)F_DIM * D_DIM;               // F*D
    ushort* Wd2T  = Wd1T + (size_t)F_DIM * D_DIM;              // F*D
    uint*   packed = (uint*)(Wd2T + (size_t)F_DIM * D_DIM);    // B*768
    float*  gramp = (float*)(packed + (size_t)B_DIM * 768);    // 10F (2 halves)
    int*    flagP = (int*)(gramp + 10 * F_DIM);                // F (contig w/ flag1,flag2)
    int*    flag1 = flagP + F_DIM;                             // F
    int*    flag2 = flag1 + F_DIM;                             // F
    float*  auxpart = (float*)(flag2 + F_DIM);                 // B
    float*  cntpart = auxpart + B_DIM;                         // B

    convert_kernel<<<1152, 512, 0, stream>>>(We, We_bf, x, x_bf);

    gemmtr_kernel<<<2560, 256, 0, stream>>>(
        x_bf, We_bf, be, packed,
        Wd, Wd1, Wd2, WdT, Wd1T, Wd2T, gramp, flagP);

    mrcra_kernel<<<B_DIM, 512, 0, stream>>>(
        packed, x, We, be, We1, be1, We2, be2, gramp,
        WdT, bd, Wd1T, bd1, Wd2T, bd2,
        flagP, flag1, flag2, auxpart, cntpart, out);

    finalize_kernel<<<1, 256, 0, stream>>>(
        flagP, flag1, flag2, auxpart, cntpart, out);
}